// Round 4
// baseline (870.512 us; speedup 1.0000x reference)
//
#include <hip/hip_runtime.h>
#include <hip/hip_bf16.h>

// Self_mask_Spectral_MSA on MI355X — Round 3: FLOAT32 I/O (per reference dtypes).
// B=4, H=W=256, C=32, heads=4, d=8. All inputs/outputs float32; intermediates bf16
// where bandwidth matters (vspec scratch, LDS tiles) — error budget ~0.005 vs 0.049 threshold.
//
// Exact algebraic simplifications:
//  - spatial attention: conv3x3(32->32)+1x1(32->1) folded to one 32->1 conv (W1); 7x7 likewise (W2).
//  - attention: per (b,head) 8x8 gram over n=65536 + norms accumulated atomically in the fused
//    q/k projection (q,k never materialized). softmax folded with proj_W into per-batch
//    32x32 M; out1 = gelu(M @ vspec_row + proj_b) computed in pos_out's epilogue.
//  - V projection fused into vspec conv staging; pos1+pos2 fused with halo recompute,
//    t MASKED to zero outside the image (pos2's zero padding is on conv1's output domain).
// Workspace: [0,32KB) small f32, [32KB,70KB) transposed bf16 pos weights, [128KB, +16MB) vspec bf16.

#define NB 4
#define NC 32
#define NS 256
#define NN 65536

typedef unsigned short u16;
typedef unsigned int u32;

__device__ __forceinline__ float bf2f(u16 s){ return __uint_as_float(((u32)s) << 16); }
__device__ __forceinline__ u16 f2bf(float x){
  u32 u = __float_as_uint(x);
  u32 r = (u + 0x7fffu + ((u >> 16) & 1u)) >> 16;   // RNE
  return (u16)r;
}
__device__ __forceinline__ void dec8(uint4 u, float* f){
  f[0] = __uint_as_float((u.x & 0xffffu) << 16);
  f[1] = __uint_as_float(u.x & 0xffff0000u);
  f[2] = __uint_as_float((u.y & 0xffffu) << 16);
  f[3] = __uint_as_float(u.y & 0xffff0000u);
  f[4] = __uint_as_float((u.z & 0xffffu) << 16);
  f[5] = __uint_as_float(u.z & 0xffff0000u);
  f[6] = __uint_as_float((u.w & 0xffffu) << 16);
  f[7] = __uint_as_float(u.w & 0xffff0000u);
}
__device__ __forceinline__ void ld32f(const float* __restrict__ p, float* x){
  const float4* q = (const float4*)p;
  #pragma unroll
  for (int k = 0; k < 8; k++){
    float4 f = q[k];
    x[4 * k] = f.x; x[4 * k + 1] = f.y; x[4 * k + 2] = f.z; x[4 * k + 3] = f.w;
  }
}
__device__ __forceinline__ uint4 pack8(const float* f){
  uint4 u;
  u.x = (u32)f2bf(f[0]) | ((u32)f2bf(f[1]) << 16);
  u.y = (u32)f2bf(f[2]) | ((u32)f2bf(f[3]) << 16);
  u.z = (u32)f2bf(f[4]) | ((u32)f2bf(f[5]) << 16);
  u.w = (u32)f2bf(f[6]) | ((u32)f2bf(f[7]) << 16);
  return u;
}
__device__ __forceinline__ float gelu_exact(float x){
  return 0.5f * x * (1.0f + erff(x * 0.70710678118654752f));
}
__device__ __forceinline__ float sigmoidf_(float x){ return 1.0f / (1.0f + expf(-x)); }

// -------------------------------------------------------------- zero accumulators
__global__ void zero_kernel(float* __restrict__ p, int n){
  for (int i = threadIdx.x; i < n; i += 256) p[i] = 0.f;
}

// ---------------------------------------------------------------- channel mask
__global__ __launch_bounds__(256) void channel_sum_kernel(const float* __restrict__ xhsi,
                                                          float* __restrict__ sums){
  int b = blockIdx.x >> 6;
  int blk = blockIdx.x & 63;
  const float* p = xhsi + (size_t)b * NN * NC;
  int t = threadIdx.x;
  int base = blk * 32768;
  float acc = 0.f;
  for (int k = 0; k < 128; k++) acc += p[base + t + k * 256];
  __shared__ float red[256];
  red[t] = acc;
  __syncthreads();
  if (t < 32){
    float s = 0.f;
    #pragma unroll
    for (int k = 0; k < 8; k++) s += red[t + k * 32];     // channel of red[j] is j&31
    atomicAdd(&sums[b * 32 + t], s);
  }
}

__global__ void channel_mask_kernel(const float* __restrict__ sums,
                                    const float* __restrict__ fc1, const float* __restrict__ fc2,
                                    float* __restrict__ cmask, float* __restrict__ out_cm){
  __shared__ float avg[NB][NC], hid[NB][NC];
  int t = threadIdx.x;            // 128
  int b = t >> 5, o = t & 31;
  avg[b][o] = sums[t] * (1.0f / 65536.0f);
  __syncthreads();
  float s = 0.f;
  for (int j = 0; j < 32; j++) s += fc1[o * 32 + j] * avg[b][j];
  hid[b][o] = fmaxf(s, 0.f);
  __syncthreads();
  float s2 = 0.f;
  for (int i = 0; i < 32; i++) s2 += fc2[o * 32 + i] * hid[b][i];
  float m = sigmoidf_(s2);
  cmask[t] = m;
  out_cm[t] = m;
}

// -------------------------------------------------------- spatial mask (folded)
__global__ void fold_sa_kernel(const float* __restrict__ c1a, const float* __restrict__ c1b,
                               const float* __restrict__ c2a, const float* __restrict__ c2b,
                               float* __restrict__ W1, float* __restrict__ W2){
  int j = threadIdx.x;            // 32
  for (int r = 0; r < 9; r++){
    float s = 0.f;
    for (int i = 0; i < 32; i++) s += c1b[i] * c1a[(i * 32 + j) * 9 + r];
    W1[r * 32 + j] = s;           // r = aw*3+ah  (aw = w-offset, ah = h-offset)
  }
  for (int r = 0; r < 49; r++){
    float s = 0.f;
    for (int i = 0; i < 32; i++) s += c2b[i] * c2a[(i * 32 + j) * 49 + r];
    W2[r * 32 + j] = s;           // r = aw*7+ah
  }
}

// transpose pos conv weights OIHW f32 [o][i][r] -> bf16 [r][i][o]
__global__ void transpose_pos_kernel(const float* __restrict__ p1, const float* __restrict__ p2,
                                     u16* __restrict__ wt1, u16* __restrict__ wt2){
  for (int idx = threadIdx.x; idx < 9216; idx += 256){
    int o = idx / 288;
    int rem = idx - o * 288;
    int i = rem / 9;
    int r = rem - i * 9;
    wt1[(r * 32 + i) * 32 + o] = f2bf(p1[idx]);
    wt2[(r * 32 + i) * 32 + o] = f2bf(p2[idx]);
  }
}

// tile: [c8][xl][yl] uint4 (8 bf16 channels per uint4). 16x16 output px, halo 3.
__global__ __launch_bounds__(256) void spatial_mask_kernel(
    const float* __restrict__ xmsi, const float* __restrict__ W1, const float* __restrict__ W2,
    const float* __restrict__ sac3, float* __restrict__ out_sm){
  __shared__ uint4 tile[4][22][25];
  __shared__ float W1s[9 * 32], W2s[49 * 32];
  int t = threadIdx.x;
  int b = blockIdx.z;
  int x0 = blockIdx.x * 16, y0 = blockIdx.y * 16;
  for (int idx = t; idx < 9 * 32;  idx += 256) W1s[idx] = W1[idx];
  for (int idx = t; idx < 49 * 32; idx += 256) W2s[idx] = W2[idx];
  for (int p = t; p < 484; p += 256){
    int xl = p / 22, yl = p - xl * 22;
    int X = x0 - 3 + xl, Y = y0 - 3 + yl;
    uint4 u0, u1, u2, u3;
    if (X >= 0 && X < NS && Y >= 0 && Y < NS){
      float xr[32];
      ld32f(xmsi + ((size_t)b * NN + (size_t)Y * NS + X) * NC, xr);
      u0 = pack8(xr); u1 = pack8(xr + 8); u2 = pack8(xr + 16); u3 = pack8(xr + 24);
    } else {
      u0 = u1 = u2 = u3 = make_uint4(0, 0, 0, 0);
    }
    tile[0][xl][yl] = u0; tile[1][xl][yl] = u1; tile[2][xl][yl] = u2; tile[3][xl][yl] = u3;
  }
  __syncthreads();
  int j = t & 15, i = t >> 4;     // j: y (h), i: x (w)
  float m1 = 0.f, m2 = 0.f;
  for (int aw = 0; aw < 7; aw++){
    for (int ah = 0; ah < 7; ah++){
      const float* wr = &W2s[(aw * 7 + ah) * 32];
      float s = 0.f;
      #pragma unroll
      for (int c = 0; c < 4; c++){
        uint4 u = tile[c][i + aw][j + ah];
        float g[8]; dec8(u, g);
        #pragma unroll
        for (int k = 0; k < 8; k++) s += g[k] * wr[c * 8 + k];
      }
      m2 += s;
    }
  }
  for (int aw = 0; aw < 3; aw++){
    for (int ah = 0; ah < 3; ah++){
      const float* wr = &W1s[(aw * 3 + ah) * 32];
      float s = 0.f;
      #pragma unroll
      for (int c = 0; c < 4; c++){
        uint4 u = tile[c][i + aw + 2][j + ah + 2];
        float g[8]; dec8(u, g);
        #pragma unroll
        for (int k = 0; k < 8; k++) s += g[k] * wr[c * 8 + k];
      }
      m1 += s;
    }
  }
  float m = sac3[0] * m1 + sac3[1] * m2;
  float sg = sigmoidf_(m);
  int x = x0 + i, y = y0 + j;
  out_sm[(size_t)b * NN + (size_t)x * NS + y] = sg;   // (b,1,w,h): w-major
}

// ---------------------------------------------------- fused q/k projection + gram
// wave: lanes 0..31 compute q_o, lanes 32..63 compute k_o for the SAME row.
// gacc[b*320 + 0..255]=G[(h*8+d)*8+e], [256..287]=nk, [288..319]=nq.
__global__ __launch_bounds__(256) void qk_gram_kernel(const float* __restrict__ xfu,
                                                      const float* __restrict__ Wq,
                                                      const float* __restrict__ Wk,
                                                      float* __restrict__ gacc){
  int t = threadIdx.x;
  int wv = t >> 6, lane = t & 63;
  int role = lane >> 5;           // 0: q, 1: k
  int o = lane & 31;
  const float* W = role ? Wk : Wq;
  float w[32];
  ld32f(W + o * 32, w);
  float Gacc[8];
  #pragma unroll
  for (int e = 0; e < 8; e++) Gacc[e] = 0.f;
  float nrm = 0.f;
  int base = blockIdx.x * 512 + wv * 128;
  int b = blockIdx.x >> 7;        // 128 blocks per batch
  for (int r = 0; r < 128; r++){
    int row = base + r;
    float xr[32];
    ld32f(xfu + (size_t)row * NC, xr);
    float s = 0.f;
    #pragma unroll
    for (int i2 = 0; i2 < 32; i2++) s += xr[i2] * w[i2];
    nrm += s * s;
    #pragma unroll
    for (int e = 0; e < 8; e++){
      float qe = __shfl(s, (o & 24) + e, 64);   // q-lane of same head, same row
      Gacc[e] += s * qe;                        // meaningful on k-lanes only
    }
  }
  __shared__ float LG[4][32][8];
  __shared__ float Lk[4][32], Lq[4][32];
  if (role){
    #pragma unroll
    for (int e = 0; e < 8; e++) LG[wv][o][e] = Gacc[e];
    Lk[wv][o] = nrm;
  } else {
    Lq[wv][o] = nrm;
  }
  __syncthreads();
  {
    int oo = t >> 3, ee = t & 7;
    float s4 = LG[0][oo][ee] + LG[1][oo][ee] + LG[2][oo][ee] + LG[3][oo][ee];
    atomicAdd(&gacc[b * 320 + t], s4);
  }
  if (t < 32){
    atomicAdd(&gacc[b * 320 + 256 + t], Lk[0][t] + Lk[1][t] + Lk[2][t] + Lk[3][t]);
  } else if (t < 64){
    int oo = t - 32;
    atomicAdd(&gacc[b * 320 + 288 + oo], Lq[0][oo] + Lq[1][oo] + Lq[2][oo] + Lq[3][oo]);
  }
}

// softmax + fold with proj_W: M[b][o][h*8+e] = sum_d projW[o][h*8+d]*attn[b,h,d,e]
__global__ void attn_m_kernel(const float* __restrict__ gacc, const float* __restrict__ projW,
                              float* __restrict__ M){
  __shared__ float attn_s[16][64];
  int t = threadIdx.x;            // 256
  if (t < 128){
    int bh = t >> 3, d = t & 7;   // bh = b*4+h
    int b = bh >> 2, h = bh & 3;
    const float* base = gacc + b * 320;
    int o = h * 8 + d;
    float nk = fmaxf(sqrtf(base[256 + o]), 1e-12f);
    float l[8];
    float mx = -1e30f;
    #pragma unroll
    for (int e = 0; e < 8; e++){
      float nq = fmaxf(sqrtf(base[288 + h * 8 + e]), 1e-12f);
      l[e] = base[o * 8 + e] / (nk * nq);
      mx = fmaxf(mx, l[e]);
    }
    float se = 0.f;
    #pragma unroll
    for (int e = 0; e < 8; e++){ l[e] = expf(l[e] - mx); se += l[e]; }
    float inv = 1.f / se;
    #pragma unroll
    for (int e = 0; e < 8; e++) attn_s[bh][d * 8 + e] = l[e] * inv;
  }
  __syncthreads();
  for (int idx = t; idx < 4096; idx += 256){
    int b = idx >> 10, o = (idx >> 5) & 31, i = idx & 31;
    int hd = i >> 3, e = i & 7;
    float s = 0.f;
    #pragma unroll
    for (int d = 0; d < 8; d++)
      s += projW[o * 32 + hd * 8 + d] * attn_s[b * 4 + hd][d * 8 + e];
    M[idx] = s;                   // [b][o][i]
  }
}

// --------------------------------------------- vspec: fused V-proj + gate + conv + residual
// gated v computed on the fly from xfu; 3x3 conv attnW; + xhsi residual -> vspec bf16 (b,n,c).
// Block: 8 x(w)-cols x 32 y(h). lanes=o (32), xs=t>>5.
__global__ __launch_bounds__(256) void vspec_kernel(
    const float* __restrict__ xfu, const float* __restrict__ Wv,
    const float* __restrict__ attnW, const float* __restrict__ out_sm,
    const float* __restrict__ cmaskf, const float* __restrict__ xhsi,
    u16* __restrict__ vspec_g){
  __shared__ u16 gv[32 * 10 * 40];              // [c][xl][yl(34,pad40)] gated v, bf16
  __shared__ u16 Wl[9 * 32 * 32];               // [r][i][o] bf16, r = aw*3+ah
  __shared__ alignas(16) float WvL[1024];       // [i][o]
  __shared__ float cml[32];
  int t = threadIdx.x;
  int b = blockIdx.z;
  int x0 = blockIdx.x * 8, y0 = blockIdx.y * 32;

  for (int idx = t; idx < 1024; idx += 256){
    int oo = idx >> 5, ii = idx & 31;
    WvL[ii * 32 + oo] = Wv[idx];                // Wv[o][i] -> [i][o]
  }
  if (t < 32) cml[t] = cmaskf[b * 32 + t];
  __syncthreads();

  for (int idx = t; idx < 9216; idx += 256){
    int oo = idx / 288;
    int rem = idx - oo * 288;
    int ii = rem / 9;
    int r = rem - ii * 9;
    Wl[(r * 32 + ii) * 32 + oo] = f2bf(attnW[idx]);
  }
  for (int p = t; p < 340; p += 256){           // 10 x 34 halo tile
    int xl = p / 34, yl = p - xl * 34;
    int X = x0 - 1 + xl, Y = y0 - 1 + yl;       // X: w, Y: h
    u16* dst = &gv[xl * 40 + yl];               // + c*400 per channel
    if (X >= 0 && X < NS && Y >= 0 && Y < NS){
      float xr[32];
      ld32f(xfu + ((size_t)b * NN + (size_t)Y * NS + X) * NC, xr);
      float sm = out_sm[(size_t)b * NN + (size_t)X * NS + Y];
      float vo[32];
      #pragma unroll
      for (int q = 0; q < 32; q++) vo[q] = 0.f;
      for (int i = 0; i < 32; i++){
        const float4* wr = (const float4*)&WvL[i * 32];
        float xv = xr[i];
        #pragma unroll
        for (int q = 0; q < 8; q++){
          float4 w4 = wr[q];
          vo[4 * q]     += xv * w4.x;
          vo[4 * q + 1] += xv * w4.y;
          vo[4 * q + 2] += xv * w4.z;
          vo[4 * q + 3] += xv * w4.w;
        }
      }
      #pragma unroll
      for (int c = 0; c < 32; c++) dst[c * 400] = f2bf(vo[c] * sm * cml[c]);
    } else {
      #pragma unroll
      for (int c = 0; c < 32; c++) dst[c * 400] = 0;
    }
  }
  __syncthreads();

  int o = t & 31, xs = t >> 5;
  float acc[32];
  #pragma unroll
  for (int yy = 0; yy < 32; yy++) acc[yy] = 0.f;
  #pragma unroll
  for (int aw = 0; aw < 3; aw++){
    for (int i2 = 0; i2 < 32; i2++){
      const uint4* rp = (const uint4*)(gv + (i2 * 10 + xs + aw) * 40);
      uint4 r0 = rp[0], r1 = rp[1], r2 = rp[2], r3 = rp[3], r4 = rp[4];
      float g[40];
      dec8(r0, g); dec8(r1, g + 8); dec8(r2, g + 16); dec8(r3, g + 24); dec8(r4, g + 32);
      const int wb = (aw * 3 * 32 + i2) * 32 + o;
      float w0 = bf2f(Wl[wb]);
      float w1 = bf2f(Wl[wb + 1024]);
      float w2 = bf2f(Wl[wb + 2048]);
      #pragma unroll
      for (int yy = 0; yy < 32; yy++)
        acc[yy] = fmaf(g[yy], w0, fmaf(g[yy + 1], w1, fmaf(g[yy + 2], w2, acc[yy])));
    }
  }
  int x = x0 + xs;
  #pragma unroll
  for (int yy = 0; yy < 32; yy++){
    size_t n = (size_t)b * NN + (size_t)(y0 + yy) * NS + x;
    vspec_g[n * NC + o] = f2bf(acc[yy] + xhsi[n * NC + o]);
  }
}

// ------------------------------------- fused pos1 -> gelu -> pos2 + out1 epilogue
// t = gelu(conv1(vspec)+b1) on the halo-1 tile (MASKED to 0 outside image);
// out = conv2(t) + b2 + gelu(M @ vspec_row + proj_b), stored (b,c,w,h) f32.
// 320 threads: (o in [0,32), xsl in [0,10)). conv2/epilogue use xsl<8.
__global__ __launch_bounds__(320) void pos_out_kernel(
    const u16* __restrict__ vspec_g, const u16* __restrict__ wt1,
    const u16* __restrict__ wt2, const float* __restrict__ pos1b,
    const float* __restrict__ pos2b, const float* __restrict__ Mf,
    const float* __restrict__ projb, float* __restrict__ outp){
  __shared__ u16 vs[32 * 12 * 40];    // [i][vxl(12)][vyl(36,pad40)]
  __shared__ u16 tt[32 * 10 * 40];    // [o][txl(10)][tyl(34,pad40)]
  __shared__ u16 wsl[3072];           // one aw-slice: [ah][i][o]
  int t = threadIdx.x;
  int b = blockIdx.z;
  int x0 = blockIdx.x * 8, y0 = blockIdx.y * 32;
  int o = t & 31, xsl = t >> 5;       // xsl in [0,10)

  for (int p = t; p < 12 * 36; p += 320){
    int vxl = p / 36, vyl = p - vxl * 36;
    int X = x0 - 2 + vxl, Y = y0 - 2 + vyl;
    u16* dst = &vs[vxl * 40 + vyl];
    if (X >= 0 && X < NS && Y >= 0 && Y < NS){
      const uint4* src = (const uint4*)(vspec_g + ((size_t)b * NN + (size_t)Y * NS + X) * NC);
      uint4 u0 = src[0], u1 = src[1], u2 = src[2], u3 = src[3];
      alignas(16) u16 raw[32];
      *(uint4*)(raw) = u0; *(uint4*)(raw + 8) = u1;
      *(uint4*)(raw + 16) = u2; *(uint4*)(raw + 24) = u3;
      #pragma unroll
      for (int i = 0; i < 32; i++) dst[i * 480] = raw[i];
    } else {
      #pragma unroll
      for (int i = 0; i < 32; i++) dst[i * 480] = 0;
    }
  }
  __syncthreads();

  // ---- conv1: t at (X = x0-1+xsl, Y = y0-1+tyl), tyl in [0,34)
  float ta[34];
  #pragma unroll
  for (int k = 0; k < 34; k++) ta[k] = 0.f;
  for (int aw = 0; aw < 3; aw++){
    for (int idx = t; idx < 3072; idx += 320) wsl[idx] = wt1[aw * 3072 + idx];
    __syncthreads();
    for (int i2 = 0; i2 < 32; i2++){
      const uint4* rp = (const uint4*)(vs + (i2 * 12 + xsl + aw) * 40);
      uint4 r0 = rp[0], r1 = rp[1], r2 = rp[2], r3 = rp[3], r4 = rp[4];
      float g[40];
      dec8(r0, g); dec8(r1, g + 8); dec8(r2, g + 16); dec8(r3, g + 24); dec8(r4, g + 32);
      float w0 = bf2f(wsl[i2 * 32 + o]);
      float w1 = bf2f(wsl[i2 * 32 + o + 1024]);
      float w2 = bf2f(wsl[i2 * 32 + o + 2048]);
      #pragma unroll
      for (int yl = 0; yl < 34; yl++)
        ta[yl] = fmaf(g[yl], w0, fmaf(g[yl + 1], w1, fmaf(g[yl + 2], w2, ta[yl])));
    }
    __syncthreads();
  }
  {
    float b1 = pos1b[o];
    int X = x0 - 1 + xsl;
    bool colOK = (X >= 0 && X < NS);
    u16* trow = &tt[(o * 10 + xsl) * 40];
    #pragma unroll
    for (int yl = 0; yl < 34; yl++){
      int Y = y0 - 1 + yl;
      float val = (colOK && Y >= 0 && Y < NS) ? gelu_exact(ta[yl] + b1) : 0.f;
      trow[yl] = f2bf(val);
    }
  }
  __syncthreads();

  // ---- conv2 + out1 epilogue (xsl < 8 active)
  float acc2[32];
  #pragma unroll
  for (int yy = 0; yy < 32; yy++) acc2[yy] = 0.f;
  for (int aw = 0; aw < 3; aw++){
    for (int idx = t; idx < 3072; idx += 320) wsl[idx] = wt2[aw * 3072 + idx];
    __syncthreads();
    if (xsl < 8){
      for (int i2 = 0; i2 < 32; i2++){
        const uint4* rp = (const uint4*)(tt + (i2 * 10 + xsl + aw) * 40);
        uint4 r0 = rp[0], r1 = rp[1], r2 = rp[2], r3 = rp[3], r4 = rp[4];
        float g[40];
        dec8(r0, g); dec8(r1, g + 8); dec8(r2, g + 16); dec8(r3, g + 24); dec8(r4, g + 32);
        float w0 = bf2f(wsl[i2 * 32 + o]);
        float w1 = bf2f(wsl[i2 * 32 + o + 1024]);
        float w2 = bf2f(wsl[i2 * 32 + o + 2048]);
        #pragma unroll
        for (int yy = 0; yy < 32; yy++)
          acc2[yy] = fmaf(g[yy], w0, fmaf(g[yy + 1], w1, fmaf(g[yy + 2], w2, acc2[yy])));
      }
    }
    __syncthreads();
  }
  if (xsl < 8){
    int x = x0 + xsl;
    float m[32];
    {
      const float4* mp = (const float4*)(Mf + b * 1024 + o * 32);
      #pragma unroll
      for (int k = 0; k < 8; k++){
        float4 f = mp[k];
        m[4 * k] = f.x; m[4 * k + 1] = f.y; m[4 * k + 2] = f.z; m[4 * k + 3] = f.w;
      }
    }
    float pb = projb[o];
    float b2v = pos2b[o];
    float outv[32];
    #pragma unroll
    for (int yy = 0; yy < 32; yy++){
      size_t n = (size_t)b * NN + (size_t)(y0 + yy) * NS + x;
      const uint4* xp = (const uint4*)(vspec_g + n * NC);
      uint4 u0 = xp[0], u1 = xp[1], u2 = xp[2], u3 = xp[3];
      float xr[32];
      dec8(u0, xr); dec8(u1, xr + 8); dec8(u2, xr + 16); dec8(u3, xr + 24);
      float s = pb;
      #pragma unroll
      for (int i2 = 0; i2 < 32; i2++) s += m[i2] * xr[i2];
      outv[yy] = acc2[yy] + b2v + gelu_exact(s);
    }
    float4* dp = (float4*)(outp + (((size_t)(b * 32 + o) * NS) + x) * NS + y0);
    #pragma unroll
    for (int k = 0; k < 8; k++)
      dp[k] = make_float4(outv[4 * k], outv[4 * k + 1], outv[4 * k + 2], outv[4 * k + 3]);
  }
}

// ---------------------------------------------------------------------- launch
extern "C" void kernel_launch(void* const* d_in, const int* in_sizes, int n_in,
                              void* d_out, int out_size, void* d_ws, size_t ws_size,
                              hipStream_t stream){
  (void)in_sizes; (void)n_in; (void)out_size; (void)ws_size;
  const float* xfu   = (const float*)d_in[0];
  const float* xmsi  = (const float*)d_in[1];
  const float* xhsi  = (const float*)d_in[2];
  const float* Wq    = (const float*)d_in[3];
  const float* Wk    = (const float*)d_in[4];
  const float* Wv    = (const float*)d_in[5];
  const float* projW = (const float*)d_in[6];
  const float* projb = (const float*)d_in[7];
  const float* pos1W = (const float*)d_in[8];
  const float* pos1b = (const float*)d_in[9];
  const float* pos2W = (const float*)d_in[10];
  const float* pos2b = (const float*)d_in[11];
  const float* cafc1 = (const float*)d_in[12];
  const float* cafc2 = (const float*)d_in[13];
  const float* sac1a = (const float*)d_in[14];
  const float* sac1b = (const float*)d_in[15];
  const float* sac2a = (const float*)d_in[16];
  const float* sac2b = (const float*)d_in[17];
  const float* sac3  = (const float*)d_in[18];
  const float* attnW = (const float*)d_in[19];

  float* out = (float*)d_out;
  float* out_main = out;                  // (b,c,w,h) 8388608 f32
  float* out_cm   = out + 8388608;        // 128
  float* out_sm   = out + 8388736;        // 262144

  // workspace map (total ~16.1 MB)
  char* ws = (char*)d_ws;
  float* sums   = (float*)(ws + 0);         // 128 f
  float* gacc   = (float*)(ws + 512);       // 1280 f
  float* cmaskf = (float*)(ws + 5632);      // 128 f
  float* W1     = (float*)(ws + 6144);      // 288 f
  float* W2     = (float*)(ws + 7296);      // 1568 f
  float* Mf     = (float*)(ws + 16384);     // 4096 f
  u16*   wt1    = (u16*)(ws + 32768);       // 9216 bf16
  u16*   wt2    = (u16*)(ws + 51200);       // 9216 bf16
  u16*   vspec  = (u16*)(ws + 131072);      // 16 MB bf16 (b,n,c)

  zero_kernel<<<1, 256, 0, stream>>>(sums, 1408);               // sums + gacc
  channel_sum_kernel<<<256, 256, 0, stream>>>(xhsi, sums);
  channel_mask_kernel<<<1, 128, 0, stream>>>(sums, cafc1, cafc2, cmaskf, out_cm);
  fold_sa_kernel<<<1, 32, 0, stream>>>(sac1a, sac1b, sac2a, sac2b, W1, W2);
  transpose_pos_kernel<<<1, 256, 0, stream>>>(pos1W, pos2W, wt1, wt2);
  spatial_mask_kernel<<<dim3(16, 16, NB), 256, 0, stream>>>(xmsi, W1, W2, sac3, out_sm);
  qk_gram_kernel<<<512, 256, 0, stream>>>(xfu, Wq, Wk, gacc);
  attn_m_kernel<<<1, 256, 0, stream>>>(gacc, projW, Mf);
  vspec_kernel<<<dim3(32, 8, NB), 256, 0, stream>>>(
      xfu, Wv, attnW, out_sm, cmaskf, xhsi, vspec);
  pos_out_kernel<<<dim3(32, 8, NB), 320, 0, stream>>>(
      vspec, wt1, wt2, pos1b, pos2b, Mf, projb, out_main);
}

// Round 5
// 733.561 us; speedup vs baseline: 1.1867x; 1.1867x over previous
//
#include <hip/hip_runtime.h>
#include <hip/hip_bf16.h>

// Self_mask_Spectral_MSA on MI355X — Round 4: split pos-conv pipeline (occupancy fix).
// B=4, H=W=256, C=32, heads=4, d=8. f32 I/O, fp32 accumulation, bf16 intermediates.
//
// R4 changes vs R3 (passed, 870us, absmax 0.0156):
//  - pos_out (398us, 62KB LDS, occ 14%) split into pos1 (vspec->t) + pos2 (t->out+out1):
//    44KB LDS each -> 3 blocks/CU, single sync, no halo recompute of conv1.
//    t buffer (16MB bf16) lives at ws+16.9MB — branched on ws_size >= 33.7MB,
//    R3's fused pos_out kept as fallback.
//  - 5 one-block setup kernels merged into pre_kernel + mid_kernel.

#define NB 4
#define NC 32
#define NS 256
#define NN 65536

typedef unsigned short u16;
typedef unsigned int u32;

__device__ __forceinline__ float bf2f(u16 s){ return __uint_as_float(((u32)s) << 16); }
__device__ __forceinline__ u16 f2bf(float x){
  u32 u = __float_as_uint(x);
  u32 r = (u + 0x7fffu + ((u >> 16) & 1u)) >> 16;   // RNE
  return (u16)r;
}
__device__ __forceinline__ void dec8(uint4 u, float* f){
  f[0] = __uint_as_float((u.x & 0xffffu) << 16);
  f[1] = __uint_as_float(u.x & 0xffff0000u);
  f[2] = __uint_as_float((u.y & 0xffffu) << 16);
  f[3] = __uint_as_float(u.y & 0xffff0000u);
  f[4] = __uint_as_float((u.z & 0xffffu) << 16);
  f[5] = __uint_as_float(u.z & 0xffff0000u);
  f[6] = __uint_as_float((u.w & 0xffffu) << 16);
  f[7] = __uint_as_float(u.w & 0xffff0000u);
}
__device__ __forceinline__ void ld32f(const float* __restrict__ p, float* x){
  const float4* q = (const float4*)p;
  #pragma unroll
  for (int k = 0; k < 8; k++){
    float4 f = q[k];
    x[4 * k] = f.x; x[4 * k + 1] = f.y; x[4 * k + 2] = f.z; x[4 * k + 3] = f.w;
  }
}
__device__ __forceinline__ uint4 pack8(const float* f){
  uint4 u;
  u.x = (u32)f2bf(f[0]) | ((u32)f2bf(f[1]) << 16);
  u.y = (u32)f2bf(f[2]) | ((u32)f2bf(f[3]) << 16);
  u.z = (u32)f2bf(f[4]) | ((u32)f2bf(f[5]) << 16);
  u.w = (u32)f2bf(f[6]) | ((u32)f2bf(f[7]) << 16);
  return u;
}
__device__ __forceinline__ float gelu_exact(float x){
  return 0.5f * x * (1.0f + erff(x * 0.70710678118654752f));
}
__device__ __forceinline__ float sigmoidf_(float x){ return 1.0f / (1.0f + expf(-x)); }

// ---------------------- pre: zero accumulators + fold SA weights + transpose pos weights
__global__ __launch_bounds__(256) void pre_kernel(
    const float* __restrict__ c1a, const float* __restrict__ c1b,
    const float* __restrict__ c2a, const float* __restrict__ c2b,
    const float* __restrict__ p1, const float* __restrict__ p2,
    float* __restrict__ zbase, float* __restrict__ W1, float* __restrict__ W2,
    u16* __restrict__ wt1, u16* __restrict__ wt2){
  int t = threadIdx.x;
  for (int i = t; i < 1408; i += 256) zbase[i] = 0.f;          // sums(128) + gacc(1280)
  for (int idx = t; idx < 288; idx += 256){                    // W1[r*32+j]
    int r = idx >> 5, j = idx & 31;
    float s = 0.f;
    for (int i = 0; i < 32; i++) s += c1b[i] * c1a[(i * 32 + j) * 9 + r];
    W1[idx] = s;
  }
  for (int idx = t; idx < 1568; idx += 256){                   // W2[r*32+j]
    int r = idx >> 5, j = idx & 31;
    float s = 0.f;
    for (int i = 0; i < 32; i++) s += c2b[i] * c2a[(i * 32 + j) * 49 + r];
    W2[idx] = s;
  }
  for (int idx = t; idx < 9216; idx += 256){                   // OIHW -> [r][i][o] bf16
    int o = idx / 288;
    int rem = idx - o * 288;
    int i = rem / 9;
    int r = rem - i * 9;
    wt1[(r * 32 + i) * 32 + o] = f2bf(p1[idx]);
    wt2[(r * 32 + i) * 32 + o] = f2bf(p2[idx]);
  }
}

// ---------------------------------------------------------------- channel sums
__global__ __launch_bounds__(256) void channel_sum_kernel(const float* __restrict__ xhsi,
                                                          float* __restrict__ sums){
  int b = blockIdx.x >> 6;
  int blk = blockIdx.x & 63;
  const float* p = xhsi + (size_t)b * NN * NC;
  int t = threadIdx.x;
  int base = blk * 32768;
  float acc = 0.f;
  for (int k = 0; k < 128; k++) acc += p[base + t + k * 256];
  __shared__ float red[256];
  red[t] = acc;
  __syncthreads();
  if (t < 32){
    float s = 0.f;
    #pragma unroll
    for (int k = 0; k < 8; k++) s += red[t + k * 32];     // channel of red[j] is j&31
    atomicAdd(&sums[b * 32 + t], s);
  }
}

// ----------------- mid: channel mask (sigmoid MLP) + attention softmax + M fold
__global__ __launch_bounds__(256) void mid_kernel(
    const float* __restrict__ sums, const float* __restrict__ fc1,
    const float* __restrict__ fc2, float* __restrict__ cmaskf, float* __restrict__ out_cm,
    const float* __restrict__ gacc, const float* __restrict__ projW, float* __restrict__ Mf){
  __shared__ float avg[NB][NC], hid[NB][NC];
  __shared__ float attn_s[16][64];
  int t = threadIdx.x;
  if (t < 128){
    int b = t >> 5, o = t & 31;
    avg[b][o] = sums[t] * (1.0f / 65536.0f);
  }
  __syncthreads();
  if (t < 128){
    int b = t >> 5, o = t & 31;
    float s = 0.f;
    for (int j = 0; j < 32; j++) s += fc1[o * 32 + j] * avg[b][j];
    hid[b][o] = fmaxf(s, 0.f);
  }
  // attention: softmax over normalized gram (independent of channel-mask path)
  if (t < 128){
    int bh = t >> 3, d = t & 7;   // bh = b*4+h
    int b = bh >> 2, h = bh & 3;
    const float* base = gacc + b * 320;
    int o = h * 8 + d;
    float nk = fmaxf(sqrtf(base[256 + o]), 1e-12f);
    float l[8];
    float mx = -1e30f;
    #pragma unroll
    for (int e = 0; e < 8; e++){
      float nq = fmaxf(sqrtf(base[288 + h * 8 + e]), 1e-12f);
      l[e] = base[o * 8 + e] / (nk * nq);
      mx = fmaxf(mx, l[e]);
    }
    float se = 0.f;
    #pragma unroll
    for (int e = 0; e < 8; e++){ l[e] = expf(l[e] - mx); se += l[e]; }
    float inv = 1.f / se;
    #pragma unroll
    for (int e = 0; e < 8; e++) attn_s[bh][d * 8 + e] = l[e] * inv;
  }
  __syncthreads();
  if (t < 128){
    int b = t >> 5, o = t & 31;
    float s2 = 0.f;
    for (int i = 0; i < 32; i++) s2 += fc2[o * 32 + i] * hid[b][i];
    float m = sigmoidf_(s2);
    cmaskf[t] = m;
    out_cm[t] = m;
  }
  for (int idx = t; idx < 4096; idx += 256){        // M[b][o][i]
    int b = idx >> 10, o = (idx >> 5) & 31, i = idx & 31;
    int hd = i >> 3, e = i & 7;
    float s = 0.f;
    #pragma unroll
    for (int d = 0; d < 8; d++)
      s += projW[o * 32 + hd * 8 + d] * attn_s[b * 4 + hd][d * 8 + e];
    Mf[idx] = s;
  }
}

// tile: [c8][xl][yl] uint4 (8 bf16 channels per uint4). 16x16 output px, halo 3.
__global__ __launch_bounds__(256) void spatial_mask_kernel(
    const float* __restrict__ xmsi, const float* __restrict__ W1, const float* __restrict__ W2,
    const float* __restrict__ sac3, float* __restrict__ out_sm){
  __shared__ uint4 tile[4][22][25];
  __shared__ float W1s[9 * 32], W2s[49 * 32];
  int t = threadIdx.x;
  int b = blockIdx.z;
  int x0 = blockIdx.x * 16, y0 = blockIdx.y * 16;
  for (int idx = t; idx < 9 * 32;  idx += 256) W1s[idx] = W1[idx];
  for (int idx = t; idx < 49 * 32; idx += 256) W2s[idx] = W2[idx];
  for (int p = t; p < 484; p += 256){
    int xl = p / 22, yl = p - xl * 22;
    int X = x0 - 3 + xl, Y = y0 - 3 + yl;
    uint4 u0, u1, u2, u3;
    if (X >= 0 && X < NS && Y >= 0 && Y < NS){
      float xr[32];
      ld32f(xmsi + ((size_t)b * NN + (size_t)Y * NS + X) * NC, xr);
      u0 = pack8(xr); u1 = pack8(xr + 8); u2 = pack8(xr + 16); u3 = pack8(xr + 24);
    } else {
      u0 = u1 = u2 = u3 = make_uint4(0, 0, 0, 0);
    }
    tile[0][xl][yl] = u0; tile[1][xl][yl] = u1; tile[2][xl][yl] = u2; tile[3][xl][yl] = u3;
  }
  __syncthreads();
  int j = t & 15, i = t >> 4;     // j: y (h), i: x (w)
  float m1 = 0.f, m2 = 0.f;
  for (int aw = 0; aw < 7; aw++){
    for (int ah = 0; ah < 7; ah++){
      const float* wr = &W2s[(aw * 7 + ah) * 32];
      float s = 0.f;
      #pragma unroll
      for (int c = 0; c < 4; c++){
        uint4 u = tile[c][i + aw][j + ah];
        float g[8]; dec8(u, g);
        #pragma unroll
        for (int k = 0; k < 8; k++) s += g[k] * wr[c * 8 + k];
      }
      m2 += s;
    }
  }
  for (int aw = 0; aw < 3; aw++){
    for (int ah = 0; ah < 3; ah++){
      const float* wr = &W1s[(aw * 3 + ah) * 32];
      float s = 0.f;
      #pragma unroll
      for (int c = 0; c < 4; c++){
        uint4 u = tile[c][i + aw + 2][j + ah + 2];
        float g[8]; dec8(u, g);
        #pragma unroll
        for (int k = 0; k < 8; k++) s += g[k] * wr[c * 8 + k];
      }
      m1 += s;
    }
  }
  float m = sac3[0] * m1 + sac3[1] * m2;
  float sg = sigmoidf_(m);
  int x = x0 + i, y = y0 + j;
  out_sm[(size_t)b * NN + (size_t)x * NS + y] = sg;   // (b,1,w,h): w-major
}

// ---------------------------------------------------- fused q/k projection + gram
__global__ __launch_bounds__(256) void qk_gram_kernel(const float* __restrict__ xfu,
                                                      const float* __restrict__ Wq,
                                                      const float* __restrict__ Wk,
                                                      float* __restrict__ gacc){
  int t = threadIdx.x;
  int wv = t >> 6, lane = t & 63;
  int role = lane >> 5;           // 0: q, 1: k
  int o = lane & 31;
  const float* W = role ? Wk : Wq;
  float w[32];
  ld32f(W + o * 32, w);
  float Gacc[8];
  #pragma unroll
  for (int e = 0; e < 8; e++) Gacc[e] = 0.f;
  float nrm = 0.f;
  int base = blockIdx.x * 512 + wv * 128;
  int b = blockIdx.x >> 7;        // 128 blocks per batch
  for (int r = 0; r < 128; r++){
    int row = base + r;
    float xr[32];
    ld32f(xfu + (size_t)row * NC, xr);
    float s = 0.f;
    #pragma unroll
    for (int i2 = 0; i2 < 32; i2++) s += xr[i2] * w[i2];
    nrm += s * s;
    #pragma unroll
    for (int e = 0; e < 8; e++){
      float qe = __shfl(s, (o & 24) + e, 64);   // q-lane of same head, same row
      Gacc[e] += s * qe;                        // meaningful on k-lanes only
    }
  }
  __shared__ float LG[4][32][8];
  __shared__ float Lk[4][32], Lq[4][32];
  if (role){
    #pragma unroll
    for (int e = 0; e < 8; e++) LG[wv][o][e] = Gacc[e];
    Lk[wv][o] = nrm;
  } else {
    Lq[wv][o] = nrm;
  }
  __syncthreads();
  {
    int oo = t >> 3, ee = t & 7;
    float s4 = LG[0][oo][ee] + LG[1][oo][ee] + LG[2][oo][ee] + LG[3][oo][ee];
    atomicAdd(&gacc[b * 320 + t], s4);
  }
  if (t < 32){
    atomicAdd(&gacc[b * 320 + 256 + t], Lk[0][t] + Lk[1][t] + Lk[2][t] + Lk[3][t]);
  } else if (t < 64){
    int oo = t - 32;
    atomicAdd(&gacc[b * 320 + 288 + oo], Lq[0][oo] + Lq[1][oo] + Lq[2][oo] + Lq[3][oo]);
  }
}

// --------------------------------------------- vspec: fused V-proj + gate + conv + residual
__global__ __launch_bounds__(256) void vspec_kernel(
    const float* __restrict__ xfu, const float* __restrict__ Wv,
    const float* __restrict__ attnW, const float* __restrict__ out_sm,
    const float* __restrict__ cmaskf, const float* __restrict__ xhsi,
    u16* __restrict__ vspec_g){
  __shared__ u16 gv[32 * 10 * 40];              // [c][xl][yl(34,pad40)] gated v, bf16
  __shared__ u16 Wl[9 * 32 * 32];               // [r][i][o] bf16, r = aw*3+ah
  __shared__ alignas(16) float WvL[1024];       // [i][o]
  __shared__ float cml[32];
  int t = threadIdx.x;
  int b = blockIdx.z;
  int x0 = blockIdx.x * 8, y0 = blockIdx.y * 32;

  for (int idx = t; idx < 1024; idx += 256){
    int oo = idx >> 5, ii = idx & 31;
    WvL[ii * 32 + oo] = Wv[idx];                // Wv[o][i] -> [i][o]
  }
  if (t < 32) cml[t] = cmaskf[b * 32 + t];
  __syncthreads();

  for (int idx = t; idx < 9216; idx += 256){
    int oo = idx / 288;
    int rem = idx - oo * 288;
    int ii = rem / 9;
    int r = rem - ii * 9;
    Wl[(r * 32 + ii) * 32 + oo] = f2bf(attnW[idx]);
  }
  for (int p = t; p < 340; p += 256){           // 10 x 34 halo tile
    int xl = p / 34, yl = p - xl * 34;
    int X = x0 - 1 + xl, Y = y0 - 1 + yl;       // X: w, Y: h
    u16* dst = &gv[xl * 40 + yl];               // + c*400 per channel
    if (X >= 0 && X < NS && Y >= 0 && Y < NS){
      float xr[32];
      ld32f(xfu + ((size_t)b * NN + (size_t)Y * NS + X) * NC, xr);
      float sm = out_sm[(size_t)b * NN + (size_t)X * NS + Y];
      float vo[32];
      #pragma unroll
      for (int q = 0; q < 32; q++) vo[q] = 0.f;
      for (int i = 0; i < 32; i++){
        const float4* wr = (const float4*)&WvL[i * 32];
        float xv = xr[i];
        #pragma unroll
        for (int q = 0; q < 8; q++){
          float4 w4 = wr[q];
          vo[4 * q]     += xv * w4.x;
          vo[4 * q + 1] += xv * w4.y;
          vo[4 * q + 2] += xv * w4.z;
          vo[4 * q + 3] += xv * w4.w;
        }
      }
      #pragma unroll
      for (int c = 0; c < 32; c++) dst[c * 400] = f2bf(vo[c] * sm * cml[c]);
    } else {
      #pragma unroll
      for (int c = 0; c < 32; c++) dst[c * 400] = 0;
    }
  }
  __syncthreads();

  int o = t & 31, xs = t >> 5;
  float acc[32];
  #pragma unroll
  for (int yy = 0; yy < 32; yy++) acc[yy] = 0.f;
  #pragma unroll
  for (int aw = 0; aw < 3; aw++){
    for (int i2 = 0; i2 < 32; i2++){
      const uint4* rp = (const uint4*)(gv + (i2 * 10 + xs + aw) * 40);
      uint4 r0 = rp[0], r1 = rp[1], r2 = rp[2], r3 = rp[3], r4 = rp[4];
      float g[40];
      dec8(r0, g); dec8(r1, g + 8); dec8(r2, g + 16); dec8(r3, g + 24); dec8(r4, g + 32);
      const int wb = (aw * 3 * 32 + i2) * 32 + o;
      float w0 = bf2f(Wl[wb]);
      float w1 = bf2f(Wl[wb + 1024]);
      float w2 = bf2f(Wl[wb + 2048]);
      #pragma unroll
      for (int yy = 0; yy < 32; yy++)
        acc[yy] = fmaf(g[yy], w0, fmaf(g[yy + 1], w1, fmaf(g[yy + 2], w2, acc[yy])));
    }
  }
  int x = x0 + xs;
  #pragma unroll
  for (int yy = 0; yy < 32; yy++){
    size_t n = (size_t)b * NN + (size_t)(y0 + yy) * NS + x;
    vspec_g[n * NC + o] = f2bf(acc[yy] + xhsi[n * NC + o]);
  }
}

// ------------------------------------------------- SPLIT PATH: pos1 (vspec -> t)
// t = gelu(conv1(vspec)+b1), exact coverage (no halo recompute). 44KB LDS.
__global__ __launch_bounds__(256) void pos1_kernel(
    const u16* __restrict__ vspec_g, const u16* __restrict__ wt1,
    const float* __restrict__ pos1b, u16* __restrict__ t_g){
  __shared__ u16 vs[32 * 10 * 40];    // [i][xl(10)][yl(34,pad40)]
  __shared__ u16 Wl[9216];            // [r][i][o]
  int t = threadIdx.x;
  int b = blockIdx.z;
  int x0 = blockIdx.x * 8, y0 = blockIdx.y * 32;
  for (int idx = t; idx < 9216; idx += 256) Wl[idx] = wt1[idx];
  for (int p = t; p < 340; p += 256){
    int xl = p / 34, yl = p - xl * 34;
    int X = x0 - 1 + xl, Y = y0 - 1 + yl;
    u16* dst = &vs[xl * 40 + yl];
    if (X >= 0 && X < NS && Y >= 0 && Y < NS){
      const uint4* src = (const uint4*)(vspec_g + ((size_t)b * NN + (size_t)Y * NS + X) * NC);
      uint4 u0 = src[0], u1 = src[1], u2 = src[2], u3 = src[3];
      alignas(16) u16 raw[32];
      *(uint4*)(raw) = u0; *(uint4*)(raw + 8) = u1;
      *(uint4*)(raw + 16) = u2; *(uint4*)(raw + 24) = u3;
      #pragma unroll
      for (int i = 0; i < 32; i++) dst[i * 400] = raw[i];
    } else {
      #pragma unroll
      for (int i = 0; i < 32; i++) dst[i * 400] = 0;
    }
  }
  __syncthreads();

  int o = t & 31, xs = t >> 5;
  float acc[32];
  #pragma unroll
  for (int yy = 0; yy < 32; yy++) acc[yy] = 0.f;
  #pragma unroll
  for (int aw = 0; aw < 3; aw++){
    for (int i2 = 0; i2 < 32; i2++){
      const uint4* rp = (const uint4*)(vs + (i2 * 10 + xs + aw) * 40);
      uint4 r0 = rp[0], r1 = rp[1], r2 = rp[2], r3 = rp[3], r4 = rp[4];
      float g[40];
      dec8(r0, g); dec8(r1, g + 8); dec8(r2, g + 16); dec8(r3, g + 24); dec8(r4, g + 32);
      const int wb = (aw * 3 * 32 + i2) * 32 + o;
      float w0 = bf2f(Wl[wb]);
      float w1 = bf2f(Wl[wb + 1024]);
      float w2 = bf2f(Wl[wb + 2048]);
      #pragma unroll
      for (int yy = 0; yy < 32; yy++)
        acc[yy] = fmaf(g[yy], w0, fmaf(g[yy + 1], w1, fmaf(g[yy + 2], w2, acc[yy])));
    }
  }
  float b1 = pos1b[o];
  int x = x0 + xs;
  #pragma unroll
  for (int yy = 0; yy < 32; yy++){
    size_t n = (size_t)b * NN + (size_t)(y0 + yy) * NS + x;
    t_g[n * NC + o] = f2bf(gelu_exact(acc[yy] + b1));
  }
}

// -------------------------------------- SPLIT PATH: pos2 (t -> out, + out1 epilogue)
// out = conv2(t) + b2 + gelu(M @ vspec_row + proj_b), stored (b,c,w,h) f32. 44KB LDS.
__global__ __launch_bounds__(256) void pos2_kernel(
    const u16* __restrict__ t_g, const u16* __restrict__ vspec_g,
    const u16* __restrict__ wt2, const float* __restrict__ pos2b,
    const float* __restrict__ Mf, const float* __restrict__ projb,
    float* __restrict__ outp){
  __shared__ u16 ts[32 * 10 * 40];    // [i][xl(10)][yl(34,pad40)]
  __shared__ u16 Wl[9216];            // [r][i][o]
  int t = threadIdx.x;
  int b = blockIdx.z;
  int x0 = blockIdx.x * 8, y0 = blockIdx.y * 32;
  for (int idx = t; idx < 9216; idx += 256) Wl[idx] = wt2[idx];
  for (int p = t; p < 340; p += 256){
    int xl = p / 34, yl = p - xl * 34;
    int X = x0 - 1 + xl, Y = y0 - 1 + yl;
    u16* dst = &ts[xl * 40 + yl];
    if (X >= 0 && X < NS && Y >= 0 && Y < NS){     // t == 0 outside image (zero pad)
      const uint4* src = (const uint4*)(t_g + ((size_t)b * NN + (size_t)Y * NS + X) * NC);
      uint4 u0 = src[0], u1 = src[1], u2 = src[2], u3 = src[3];
      alignas(16) u16 raw[32];
      *(uint4*)(raw) = u0; *(uint4*)(raw + 8) = u1;
      *(uint4*)(raw + 16) = u2; *(uint4*)(raw + 24) = u3;
      #pragma unroll
      for (int i = 0; i < 32; i++) dst[i * 400] = raw[i];
    } else {
      #pragma unroll
      for (int i = 0; i < 32; i++) dst[i * 400] = 0;
    }
  }
  __syncthreads();

  int o = t & 31, xs = t >> 5;
  float acc2[32];
  #pragma unroll
  for (int yy = 0; yy < 32; yy++) acc2[yy] = 0.f;
  #pragma unroll
  for (int aw = 0; aw < 3; aw++){
    for (int i2 = 0; i2 < 32; i2++){
      const uint4* rp = (const uint4*)(ts + (i2 * 10 + xs + aw) * 40);
      uint4 r0 = rp[0], r1 = rp[1], r2 = rp[2], r3 = rp[3], r4 = rp[4];
      float g[40];
      dec8(r0, g); dec8(r1, g + 8); dec8(r2, g + 16); dec8(r3, g + 24); dec8(r4, g + 32);
      const int wb = (aw * 3 * 32 + i2) * 32 + o;
      float w0 = bf2f(Wl[wb]);
      float w1 = bf2f(Wl[wb + 1024]);
      float w2 = bf2f(Wl[wb + 2048]);
      #pragma unroll
      for (int yy = 0; yy < 32; yy++)
        acc2[yy] = fmaf(g[yy], w0, fmaf(g[yy + 1], w1, fmaf(g[yy + 2], w2, acc2[yy])));
    }
  }
  int x = x0 + xs;
  float m[32];
  {
    const float4* mp = (const float4*)(Mf + b * 1024 + o * 32);
    #pragma unroll
    for (int k = 0; k < 8; k++){
      float4 f = mp[k];
      m[4 * k] = f.x; m[4 * k + 1] = f.y; m[4 * k + 2] = f.z; m[4 * k + 3] = f.w;
    }
  }
  float pb = projb[o];
  float b2v = pos2b[o];
  float outv[32];
  #pragma unroll
  for (int yy = 0; yy < 32; yy++){
    size_t n = (size_t)b * NN + (size_t)(y0 + yy) * NS + x;
    const uint4* xp = (const uint4*)(vspec_g + n * NC);
    uint4 u0 = xp[0], u1 = xp[1], u2 = xp[2], u3 = xp[3];
    float xr[32];
    dec8(u0, xr); dec8(u1, xr + 8); dec8(u2, xr + 16); dec8(u3, xr + 24);
    float s = pb;
    #pragma unroll
    for (int i2 = 0; i2 < 32; i2++) s += m[i2] * xr[i2];
    outv[yy] = acc2[yy] + b2v + gelu_exact(s);
  }
  float4* dp = (float4*)(outp + (((size_t)(b * 32 + o) * NS) + x) * NS + y0);
  #pragma unroll
  for (int k = 0; k < 8; k++)
    dp[k] = make_float4(outv[4 * k], outv[4 * k + 1], outv[4 * k + 2], outv[4 * k + 3]);
}

// ------------------------- FALLBACK PATH (ws too small): R3's fused pos_out, proven
__global__ __launch_bounds__(320) void pos_out_kernel(
    const u16* __restrict__ vspec_g, const u16* __restrict__ wt1,
    const u16* __restrict__ wt2, const float* __restrict__ pos1b,
    const float* __restrict__ pos2b, const float* __restrict__ Mf,
    const float* __restrict__ projb, float* __restrict__ outp){
  __shared__ u16 vs[32 * 12 * 40];    // [i][vxl(12)][vyl(36,pad40)]
  __shared__ u16 tt[32 * 10 * 40];    // [o][txl(10)][tyl(34,pad40)]
  __shared__ u16 wsl[3072];           // one aw-slice: [ah][i][o]
  int t = threadIdx.x;
  int b = blockIdx.z;
  int x0 = blockIdx.x * 8, y0 = blockIdx.y * 32;
  int o = t & 31, xsl = t >> 5;       // xsl in [0,10)

  for (int p = t; p < 12 * 36; p += 320){
    int vxl = p / 36, vyl = p - vxl * 36;
    int X = x0 - 2 + vxl, Y = y0 - 2 + vyl;
    u16* dst = &vs[vxl * 40 + vyl];
    if (X >= 0 && X < NS && Y >= 0 && Y < NS){
      const uint4* src = (const uint4*)(vspec_g + ((size_t)b * NN + (size_t)Y * NS + X) * NC);
      uint4 u0 = src[0], u1 = src[1], u2 = src[2], u3 = src[3];
      alignas(16) u16 raw[32];
      *(uint4*)(raw) = u0; *(uint4*)(raw + 8) = u1;
      *(uint4*)(raw + 16) = u2; *(uint4*)(raw + 24) = u3;
      #pragma unroll
      for (int i = 0; i < 32; i++) dst[i * 480] = raw[i];
    } else {
      #pragma unroll
      for (int i = 0; i < 32; i++) dst[i * 480] = 0;
    }
  }
  __syncthreads();

  float ta[34];
  #pragma unroll
  for (int k = 0; k < 34; k++) ta[k] = 0.f;
  for (int aw = 0; aw < 3; aw++){
    for (int idx = t; idx < 3072; idx += 320) wsl[idx] = wt1[aw * 3072 + idx];
    __syncthreads();
    for (int i2 = 0; i2 < 32; i2++){
      const uint4* rp = (const uint4*)(vs + (i2 * 12 + xsl + aw) * 40);
      uint4 r0 = rp[0], r1 = rp[1], r2 = rp[2], r3 = rp[3], r4 = rp[4];
      float g[40];
      dec8(r0, g); dec8(r1, g + 8); dec8(r2, g + 16); dec8(r3, g + 24); dec8(r4, g + 32);
      float w0 = bf2f(wsl[i2 * 32 + o]);
      float w1 = bf2f(wsl[i2 * 32 + o + 1024]);
      float w2 = bf2f(wsl[i2 * 32 + o + 2048]);
      #pragma unroll
      for (int yl = 0; yl < 34; yl++)
        ta[yl] = fmaf(g[yl], w0, fmaf(g[yl + 1], w1, fmaf(g[yl + 2], w2, ta[yl])));
    }
    __syncthreads();
  }
  {
    float b1 = pos1b[o];
    int X = x0 - 1 + xsl;
    bool colOK = (X >= 0 && X < NS);
    u16* trow = &tt[(o * 10 + xsl) * 40];
    #pragma unroll
    for (int yl = 0; yl < 34; yl++){
      int Y = y0 - 1 + yl;
      float val = (colOK && Y >= 0 && Y < NS) ? gelu_exact(ta[yl] + b1) : 0.f;
      trow[yl] = f2bf(val);
    }
  }
  __syncthreads();

  float acc2[32];
  #pragma unroll
  for (int yy = 0; yy < 32; yy++) acc2[yy] = 0.f;
  for (int aw = 0; aw < 3; aw++){
    for (int idx = t; idx < 3072; idx += 320) wsl[idx] = wt2[aw * 3072 + idx];
    __syncthreads();
    if (xsl < 8){
      for (int i2 = 0; i2 < 32; i2++){
        const uint4* rp = (const uint4*)(tt + (i2 * 10 + xsl + aw) * 40);
        uint4 r0 = rp[0], r1 = rp[1], r2 = rp[2], r3 = rp[3], r4 = rp[4];
        float g[40];
        dec8(r0, g); dec8(r1, g + 8); dec8(r2, g + 16); dec8(r3, g + 24); dec8(r4, g + 32);
        float w0 = bf2f(wsl[i2 * 32 + o]);
        float w1 = bf2f(wsl[i2 * 32 + o + 1024]);
        float w2 = bf2f(wsl[i2 * 32 + o + 2048]);
        #pragma unroll
        for (int yy = 0; yy < 32; yy++)
          acc2[yy] = fmaf(g[yy], w0, fmaf(g[yy + 1], w1, fmaf(g[yy + 2], w2, acc2[yy])));
      }
    }
    __syncthreads();
  }
  if (xsl < 8){
    int x = x0 + xsl;
    float m[32];
    {
      const float4* mp = (const float4*)(Mf + b * 1024 + o * 32);
      #pragma unroll
      for (int k = 0; k < 8; k++){
        float4 f = mp[k];
        m[4 * k] = f.x; m[4 * k + 1] = f.y; m[4 * k + 2] = f.z; m[4 * k + 3] = f.w;
      }
    }
    float pb = projb[o];
    float b2v = pos2b[o];
    float outv[32];
    #pragma unroll
    for (int yy = 0; yy < 32; yy++){
      size_t n = (size_t)b * NN + (size_t)(y0 + yy) * NS + x;
      const uint4* xp = (const uint4*)(vspec_g + n * NC);
      uint4 u0 = xp[0], u1 = xp[1], u2 = xp[2], u3 = xp[3];
      float xr[32];
      dec8(u0, xr); dec8(u1, xr + 8); dec8(u2, xr + 16); dec8(u3, xr + 24);
      float s = pb;
      #pragma unroll
      for (int i2 = 0; i2 < 32; i2++) s += m[i2] * xr[i2];
      outv[yy] = acc2[yy] + b2v + gelu_exact(s);
    }
    float4* dp = (float4*)(outp + (((size_t)(b * 32 + o) * NS) + x) * NS + y0);
    #pragma unroll
    for (int k = 0; k < 8; k++)
      dp[k] = make_float4(outv[4 * k], outv[4 * k + 1], outv[4 * k + 2], outv[4 * k + 3]);
  }
}

// ---------------------------------------------------------------------- launch
extern "C" void kernel_launch(void* const* d_in, const int* in_sizes, int n_in,
                              void* d_out, int out_size, void* d_ws, size_t ws_size,
                              hipStream_t stream){
  (void)in_sizes; (void)n_in; (void)out_size;
  const float* xfu   = (const float*)d_in[0];
  const float* xmsi  = (const float*)d_in[1];
  const float* xhsi  = (const float*)d_in[2];
  const float* Wq    = (const float*)d_in[3];
  const float* Wk    = (const float*)d_in[4];
  const float* Wv    = (const float*)d_in[5];
  const float* projW = (const float*)d_in[6];
  const float* projb = (const float*)d_in[7];
  const float* pos1W = (const float*)d_in[8];
  const float* pos1b = (const float*)d_in[9];
  const float* pos2W = (const float*)d_in[10];
  const float* pos2b = (const float*)d_in[11];
  const float* cafc1 = (const float*)d_in[12];
  const float* cafc2 = (const float*)d_in[13];
  const float* sac1a = (const float*)d_in[14];
  const float* sac1b = (const float*)d_in[15];
  const float* sac2a = (const float*)d_in[16];
  const float* sac2b = (const float*)d_in[17];
  const float* sac3  = (const float*)d_in[18];
  const float* attnW = (const float*)d_in[19];

  float* out = (float*)d_out;
  float* out_main = out;                  // (b,c,w,h) 8388608 f32
  float* out_cm   = out + 8388608;        // 128
  float* out_sm   = out + 8388736;        // 262144

  // workspace map: small [0,32K), wt [32K,70K), vspec [128K, +16M), t [+16M, +32M)
  char* ws = (char*)d_ws;
  float* sums   = (float*)(ws + 0);         // 128 f   (zeroed with gacc: 1408 f total)
  float* gacc   = (float*)(ws + 512);       // 1280 f
  float* cmaskf = (float*)(ws + 5632);      // 128 f
  float* W1     = (float*)(ws + 6144);      // 288 f
  float* W2     = (float*)(ws + 7296);      // 1568 f
  float* Mf     = (float*)(ws + 16384);     // 4096 f
  u16*   wt1    = (u16*)(ws + 32768);       // 9216 bf16
  u16*   wt2    = (u16*)(ws + 51200);       // 9216 bf16
  u16*   vspec  = (u16*)(ws + 131072);      // 16 MB bf16 (b,n,c)
  u16*   t_g    = (u16*)(ws + 131072 + 16777216);   // 16 MB bf16 (split path only)
  const bool split = ws_size >= (size_t)(131072 + 2 * 16777216);

  pre_kernel<<<1, 256, 0, stream>>>(sac1a, sac1b, sac2a, sac2b, pos1W, pos2W,
                                    sums, W1, W2, wt1, wt2);
  channel_sum_kernel<<<256, 256, 0, stream>>>(xhsi, sums);
  spatial_mask_kernel<<<dim3(16, 16, NB), 256, 0, stream>>>(xmsi, W1, W2, sac3, out_sm);
  qk_gram_kernel<<<512, 256, 0, stream>>>(xfu, Wq, Wk, gacc);
  mid_kernel<<<1, 256, 0, stream>>>(sums, cafc1, cafc2, cmaskf, out_cm, gacc, projW, Mf);
  vspec_kernel<<<dim3(32, 8, NB), 256, 0, stream>>>(
      xfu, Wv, attnW, out_sm, cmaskf, xhsi, vspec);
  if (split){
    pos1_kernel<<<dim3(32, 8, NB), 256, 0, stream>>>(vspec, wt1, pos1b, t_g);
    pos2_kernel<<<dim3(32, 8, NB), 256, 0, stream>>>(t_g, vspec, wt2, pos2b, Mf, projb, out_main);
  } else {
    pos_out_kernel<<<dim3(32, 8, NB), 320, 0, stream>>>(
        vspec, wt1, wt2, pos1b, pos2b, Mf, projb, out_main);
  }
}